// Round 1
// baseline (360.339 us; speedup 1.0000x reference)
//
#include <hip/hip_runtime.h>
#include <hip/hip_bf16.h>

typedef __attribute__((ext_vector_type(8))) short bf16x8;
typedef __attribute__((ext_vector_type(4))) float f32x4;

#define LOG2E 1.4426950408889634f

__device__ inline unsigned short f2bf(float f) {
  union { float f; unsigned u; } x; x.f = f;
  unsigned u = x.u;
  unsigned r = u + 0x7FFFu + ((u >> 16) & 1u);
  return (unsigned short)(r >> 16);
}

// ---------------- GEMM1: qkv = hs @ w_attn + b_attn -> scatter to q/k/v [B,H,S,Dh] bf16
__global__ __launch_bounds__(256) void gemm_qkv(
    const float* __restrict__ A, const float* __restrict__ B,
    const float* __restrict__ bias,
    unsigned short* __restrict__ qw, unsigned short* __restrict__ kw,
    unsigned short* __restrict__ vw) {
  const int K = 1024, N = 3072;
  __shared__ unsigned short Al[128][40];
  __shared__ unsigned short Bl[128][40];  // Bt[n][k]
  const int t = threadIdx.x;
  const int lane = t & 63, wid = t >> 6;
  const int wr = (wid >> 1) * 64, wc = (wid & 1) * 64;
  const int row0 = blockIdx.y * 128, col0 = blockIdx.x * 128;
  const int lr = lane & 15, lk = (lane >> 4) * 8;
  f32x4 acc[4][4] = {};
  for (int k0 = 0; k0 < K; k0 += 32) {
#pragma unroll
    for (int i = 0; i < 4; ++i) {
      int idx = t + i * 256;
      int r = idx >> 3, c = (idx & 7) << 2;
      const float4 v = *reinterpret_cast<const float4*>(&A[(size_t)(row0 + r) * K + k0 + c]);
      ushort4 b4;
      b4.x = f2bf(v.x); b4.y = f2bf(v.y); b4.z = f2bf(v.z); b4.w = f2bf(v.w);
      *reinterpret_cast<ushort4*>(&Al[r][c]) = b4;
    }
#pragma unroll
    for (int i = 0; i < 4; ++i) {
      int idx = t + i * 256;
      int kk = idx >> 5, n = (idx & 31) << 2;
      const float4 v = *reinterpret_cast<const float4*>(&B[(size_t)(k0 + kk) * N + col0 + n]);
      Bl[n + 0][kk] = f2bf(v.x);
      Bl[n + 1][kk] = f2bf(v.y);
      Bl[n + 2][kk] = f2bf(v.z);
      Bl[n + 3][kk] = f2bf(v.w);
    }
    __syncthreads();
    bf16x8 af[4], bfv[4];
#pragma unroll
    for (int mm = 0; mm < 4; ++mm)
      af[mm] = *reinterpret_cast<const bf16x8*>(&Al[wr + mm * 16 + lr][lk]);
#pragma unroll
    for (int nn = 0; nn < 4; ++nn)
      bfv[nn] = *reinterpret_cast<const bf16x8*>(&Bl[wc + nn * 16 + lr][lk]);
#pragma unroll
    for (int mm = 0; mm < 4; ++mm)
#pragma unroll
      for (int nn = 0; nn < 4; ++nn)
        acc[mm][nn] = __builtin_amdgcn_mfma_f32_16x16x32_bf16(af[mm], bfv[nn], acc[mm][nn], 0, 0, 0);
    __syncthreads();
  }
  const int rbase = (lane >> 4) * 4;
#pragma unroll
  for (int mm = 0; mm < 4; ++mm) {
#pragma unroll
    for (int nn = 0; nn < 4; ++nn) {
      int c = col0 + wc + nn * 16 + lr;
      int which = c >> 10;
      int d = c & 1023;
      int h = d >> 6, dh = d & 63;
      unsigned short* dst = (which == 0) ? qw : (which == 1) ? kw : vw;
      float bv = bias[c];
#pragma unroll
      for (int r = 0; r < 4; ++r) {
        int m = row0 + wr + mm * 16 + rbase + r;
        int b = m >> 11, s = m & 2047;
        dst[(((size_t)b * 16 + h) * 2048 + s) * 64 + dh] = f2bf(acc[mm][nn][r] + bv);
      }
    }
  }
}

// ---------------- Flash attention: per (b,h,q-tile of 128). 4 waves, KV tile = 64.
__global__ __launch_bounds__(256) void attn_kernel(
    const unsigned short* __restrict__ qw, const unsigned short* __restrict__ kw,
    const unsigned short* __restrict__ vw, unsigned short* __restrict__ ow) {
  const int S = 2048, Dh = 64;
  __shared__ unsigned short Ql[128][72];
  __shared__ unsigned short Kl[64][72];
  __shared__ unsigned short Vt[64][72];   // Vt[dh][key]
  __shared__ unsigned short Pl[4][32][72];
  const int t = threadIdx.x, lane = t & 63, wid = t >> 6;
  const int qt = blockIdx.x, bh = blockIdx.y;
  const int b = bh >> 4, h = bh & 15;
  const unsigned short* Qg = qw + (size_t)bh * S * Dh + (size_t)qt * 128 * Dh;
  const unsigned short* Kg = kw + (size_t)bh * S * Dh;
  const unsigned short* Vg = vw + (size_t)bh * S * Dh;
  const int lr = lane & 15, lk = (lane >> 4) * 8;

#pragma unroll
  for (int i = 0; i < 4; ++i) {
    int idx = t + i * 256;
    int r = idx >> 3, c = (idx & 7) << 3;
    *reinterpret_cast<int4*>(&Ql[r][c]) = *reinterpret_cast<const int4*>(&Qg[r * 64 + c]);
  }
  __syncthreads();
  bf16x8 qf[2][2];
#pragma unroll
  for (int mm = 0; mm < 2; ++mm)
#pragma unroll
    for (int kk = 0; kk < 2; ++kk)
      qf[mm][kk] = *reinterpret_cast<const bf16x8*>(&Ql[wid * 32 + mm * 16 + lr][kk * 32 + lk]);

  float mrun[2][4], lrun[2][4];
  f32x4 o[2][4] = {};
#pragma unroll
  for (int mm = 0; mm < 2; ++mm)
#pragma unroll
    for (int r = 0; r < 4; ++r) { mrun[mm][r] = -INFINITY; lrun[mm][r] = 0.f; }

  for (int kt = 0; kt < 32; ++kt) {
    const unsigned short* Kt = Kg + (size_t)kt * 64 * 64;
    const unsigned short* Vg2 = Vg + (size_t)kt * 64 * 64;
#pragma unroll
    for (int i = 0; i < 2; ++i) {
      int idx = t + i * 256;
      int r = idx >> 3, c = (idx & 7) << 3;
      *reinterpret_cast<int4*>(&Kl[r][c]) = *reinterpret_cast<const int4*>(&Kt[r * 64 + c]);
    }
#pragma unroll
    for (int i = 0; i < 4; ++i) {
      int idx = t + i * 256;
      int key = idx >> 4, d4 = (idx & 15) << 2;
      ushort4 v = *reinterpret_cast<const ushort4*>(&Vg2[key * 64 + d4]);
      Vt[d4 + 0][key] = v.x;
      Vt[d4 + 1][key] = v.y;
      Vt[d4 + 2][key] = v.z;
      Vt[d4 + 3][key] = v.w;
    }
    __syncthreads();

    // QK^T
    f32x4 sc[2][4];
#pragma unroll
    for (int mm = 0; mm < 2; ++mm) {
#pragma unroll
      for (int kf = 0; kf < 4; ++kf) {
        f32x4 s = {0.f, 0.f, 0.f, 0.f};
#pragma unroll
        for (int kk = 0; kk < 2; ++kk)
          s = __builtin_amdgcn_mfma_f32_16x16x32_bf16(
              qf[mm][kk],
              *reinterpret_cast<const bf16x8*>(&Kl[kf * 16 + lr][kk * 32 + lk]), s, 0, 0, 0);
        sc[mm][kf] = s * 0.125f;
      }
    }

    // online softmax (rows live on each 16-lane group)
#pragma unroll
    for (int mm = 0; mm < 2; ++mm) {
#pragma unroll
      for (int r = 0; r < 4; ++r) {
        float tm = fmaxf(fmaxf(sc[mm][0][r], sc[mm][1][r]), fmaxf(sc[mm][2][r], sc[mm][3][r]));
        tm = fmaxf(tm, __shfl_xor(tm, 1));
        tm = fmaxf(tm, __shfl_xor(tm, 2));
        tm = fmaxf(tm, __shfl_xor(tm, 4));
        tm = fmaxf(tm, __shfl_xor(tm, 8));
        float mnew = fmaxf(mrun[mm][r], tm);
        float alpha = exp2f((mrun[mm][r] - mnew) * LOG2E);
        mrun[mm][r] = mnew;
        float ps = 0.f;
#pragma unroll
        for (int kf = 0; kf < 4; ++kf) {
          float p = exp2f((sc[mm][kf][r] - mnew) * LOG2E);
          sc[mm][kf][r] = p;
          ps += p;
        }
        ps += __shfl_xor(ps, 1);
        ps += __shfl_xor(ps, 2);
        ps += __shfl_xor(ps, 4);
        ps += __shfl_xor(ps, 8);
        lrun[mm][r] = lrun[mm][r] * alpha + ps;
#pragma unroll
        for (int n = 0; n < 4; ++n) o[mm][n][r] *= alpha;
      }
    }

    // P -> LDS (transpose to A-fragment layout)
#pragma unroll
    for (int mm = 0; mm < 2; ++mm)
#pragma unroll
      for (int kf = 0; kf < 4; ++kf)
#pragma unroll
        for (int r = 0; r < 4; ++r)
          Pl[wid][mm * 16 + (lane >> 4) * 4 + r][kf * 16 + lr] = f2bf(sc[mm][kf][r]);
    asm volatile("s_waitcnt lgkmcnt(0)" ::: "memory");
    __builtin_amdgcn_sched_barrier(0);

    // PV
#pragma unroll
    for (int mm = 0; mm < 2; ++mm) {
      bf16x8 pf0 = *reinterpret_cast<const bf16x8*>(&Pl[wid][mm * 16 + lr][lk]);
      bf16x8 pf1 = *reinterpret_cast<const bf16x8*>(&Pl[wid][mm * 16 + lr][32 + lk]);
#pragma unroll
      for (int n = 0; n < 4; ++n) {
        o[mm][n] = __builtin_amdgcn_mfma_f32_16x16x32_bf16(
            pf0, *reinterpret_cast<const bf16x8*>(&Vt[n * 16 + lr][lk]), o[mm][n], 0, 0, 0);
        o[mm][n] = __builtin_amdgcn_mfma_f32_16x16x32_bf16(
            pf1, *reinterpret_cast<const bf16x8*>(&Vt[n * 16 + lr][32 + lk]), o[mm][n], 0, 0, 0);
      }
    }
    __syncthreads();
  }

  // epilogue: ow layout [b][s][h*64+dh]
#pragma unroll
  for (int mm = 0; mm < 2; ++mm) {
#pragma unroll
    for (int n = 0; n < 4; ++n) {
#pragma unroll
      for (int r = 0; r < 4; ++r) {
        int srow = qt * 128 + wid * 32 + mm * 16 + (lane >> 4) * 4 + r;
        int dh = n * 16 + lr;
        float val = o[mm][n][r] / lrun[mm][r];
        ow[(((size_t)b * 2048 + srow) * 16 + h) * 64 + dh] = f2bf(val);
      }
    }
  }
}

// ---------------- GEMM2: out = attn_out @ w_proj + b_proj (f32 out)
__global__ __launch_bounds__(256) void gemm_proj(
    const unsigned short* __restrict__ A, const float* __restrict__ B,
    const float* __restrict__ bias, float* __restrict__ out) {
  const int K = 1024, N = 1024;
  __shared__ unsigned short Al[128][40];
  __shared__ unsigned short Bl[128][40];
  const int t = threadIdx.x;
  const int lane = t & 63, wid = t >> 6;
  const int wr = (wid >> 1) * 64, wc = (wid & 1) * 64;
  const int row0 = blockIdx.y * 128, col0 = blockIdx.x * 128;
  const int lr = lane & 15, lk = (lane >> 4) * 8;
  f32x4 acc[4][4] = {};
  for (int k0 = 0; k0 < K; k0 += 32) {
#pragma unroll
    for (int i = 0; i < 2; ++i) {
      int idx = t + i * 256;
      int r = idx >> 2, c = (idx & 3) << 3;
      *reinterpret_cast<int4*>(&Al[r][c]) =
          *reinterpret_cast<const int4*>(&A[(size_t)(row0 + r) * K + k0 + c]);
    }
#pragma unroll
    for (int i = 0; i < 4; ++i) {
      int idx = t + i * 256;
      int kk = idx >> 5, n = (idx & 31) << 2;
      const float4 v = *reinterpret_cast<const float4*>(&B[(size_t)(k0 + kk) * N + col0 + n]);
      Bl[n + 0][kk] = f2bf(v.x);
      Bl[n + 1][kk] = f2bf(v.y);
      Bl[n + 2][kk] = f2bf(v.z);
      Bl[n + 3][kk] = f2bf(v.w);
    }
    __syncthreads();
    bf16x8 af[4], bfv[4];
#pragma unroll
    for (int mm = 0; mm < 4; ++mm)
      af[mm] = *reinterpret_cast<const bf16x8*>(&Al[wr + mm * 16 + lr][lk]);
#pragma unroll
    for (int nn = 0; nn < 4; ++nn)
      bfv[nn] = *reinterpret_cast<const bf16x8*>(&Bl[wc + nn * 16 + lr][lk]);
#pragma unroll
    for (int mm = 0; mm < 4; ++mm)
#pragma unroll
      for (int nn = 0; nn < 4; ++nn)
        acc[mm][nn] = __builtin_amdgcn_mfma_f32_16x16x32_bf16(af[mm], bfv[nn], acc[mm][nn], 0, 0, 0);
    __syncthreads();
  }
  const int rbase = (lane >> 4) * 4;
#pragma unroll
  for (int mm = 0; mm < 4; ++mm) {
#pragma unroll
    for (int nn = 0; nn < 4; ++nn) {
      int c = col0 + wc + nn * 16 + lr;
      float bv = bias[c];
#pragma unroll
      for (int r = 0; r < 4; ++r) {
        int m = row0 + wr + mm * 16 + rbase + r;
        out[(size_t)m * N + c] = acc[mm][nn][r] + bv;
      }
    }
  }
}

extern "C" void kernel_launch(void* const* d_in, const int* in_sizes, int n_in,
                              void* d_out, int out_size, void* d_ws, size_t ws_size,
                              hipStream_t stream) {
  const float* hs = (const float*)d_in[0];
  const float* w_attn = (const float*)d_in[1];
  const float* b_attn = (const float*)d_in[2];
  const float* w_proj = (const float*)d_in[3];
  const float* b_proj = (const float*)d_in[4];
  float* out = (float*)d_out;

  const size_t HEAD_ELEMS = (size_t)2 * 16 * 2048 * 64;  // 4,194,304
  unsigned short* qw = (unsigned short*)d_ws;
  unsigned short* kw = qw + HEAD_ELEMS;
  unsigned short* vw = kw + HEAD_ELEMS;
  unsigned short* ow = vw + HEAD_ELEMS;

  dim3 blk(256, 1, 1);
  dim3 g1(24, 32, 1);  // N=3072/128, M=4096/128
  gemm_qkv<<<g1, blk, 0, stream>>>(hs, w_attn, b_attn, qw, kw, vw);

  dim3 ga(16, 32, 1);  // S/128 q-tiles, B*H
  attn_kernel<<<ga, blk, 0, stream>>>(qw, kw, vw, ow);

  dim3 g2(8, 32, 1);  // N=1024/128, M=4096/128
  gemm_proj<<<g2, blk, 0, stream>>>(ow, w_proj, b_proj, out);
}

// Round 2
// 210.652 us; speedup vs baseline: 1.7106x; 1.7106x over previous
//
#include <hip/hip_runtime.h>
#include <hip/hip_bf16.h>

typedef __attribute__((ext_vector_type(8))) short bf16x8;
typedef __attribute__((ext_vector_type(4))) float f32x4;

#define LOG2E 1.4426950408889634f

__device__ inline unsigned short f2bf(float f) {
  union { float f; unsigned u; } x; x.f = f;
  unsigned u = x.u;
  unsigned r = u + 0x7FFFu + ((u >> 16) & 1u);
  return (unsigned short)(r >> 16);
}

__device__ inline void gload16(const unsigned short* g, unsigned short* l) {
  __builtin_amdgcn_global_load_lds(
      (const __attribute__((address_space(1))) unsigned int*)g,
      (__attribute__((address_space(3))) unsigned int*)l, 16, 0, 0);
}

// ---------------- prep: f32 -> bf16 elementwise
__global__ __launch_bounds__(256) void cvt_bf16(const float* __restrict__ X,
                                                unsigned short* __restrict__ Y, int n4) {
  int i = blockIdx.x * blockDim.x + threadIdx.x;
  int stride = gridDim.x * blockDim.x;
  for (; i < n4; i += stride) {
    float4 v = reinterpret_cast<const float4*>(X)[i];
    ushort4 o;
    o.x = f2bf(v.x); o.y = f2bf(v.y); o.z = f2bf(v.z); o.w = f2bf(v.w);
    reinterpret_cast<ushort4*>(Y)[i] = o;
  }
}

// ---------------- prep: W[K][N] f32 -> WT[N][K] bf16 (64x64 tiles via LDS)
__global__ __launch_bounds__(256) void transpose_cvt(const float* __restrict__ W,
                                                     unsigned short* __restrict__ WT,
                                                     int K, int N) {
  __shared__ unsigned short Tl[64][72];
  const int t = threadIdx.x;
  const int n0 = blockIdx.x * 64, k0 = blockIdx.y * 64;
#pragma unroll
  for (int i = 0; i < 4; ++i) {
    int idx = t + i * 256;
    int r = idx >> 4, c4 = (idx & 15) << 2;  // r: k-local, c4: n-local
    float4 v = *reinterpret_cast<const float4*>(&W[(size_t)(k0 + r) * N + n0 + c4]);
    Tl[c4 + 0][r] = f2bf(v.x);
    Tl[c4 + 1][r] = f2bf(v.y);
    Tl[c4 + 2][r] = f2bf(v.z);
    Tl[c4 + 3][r] = f2bf(v.w);
  }
  __syncthreads();
#pragma unroll
  for (int i = 0; i < 2; ++i) {
    int idx = t + i * 256;
    int rr = idx >> 3, cc = (idx & 7) << 3;  // rr: n-local, cc: k-local
    *reinterpret_cast<int4*>(&WT[(size_t)(n0 + rr) * K + k0 + cc]) =
        *reinterpret_cast<const int4*>(&Tl[rr][cc]);
  }
}

// ---------------- GEMM1: qkv = hs_b @ wT^T + b_attn -> scatter q/k (bhsd), v transposed blocks
__global__ __launch_bounds__(256) void gemm_qkv_b(
    const unsigned short* __restrict__ A,   // [4096][1024] bf16
    const unsigned short* __restrict__ Bt,  // [3072][1024] bf16
    const float* __restrict__ bias,
    unsigned short* __restrict__ qw, unsigned short* __restrict__ kw,
    unsigned short* __restrict__ vtg) {
  const int K = 1024;
  __shared__ unsigned short Al[4096];
  __shared__ unsigned short Bl[4096];
  const int t = threadIdx.x, lane = t & 63, wid = t >> 6;
  const int wr = (wid >> 1) * 64, wc = (wid & 1) * 64;
  const int row0 = blockIdx.y * 128, col0 = blockIdx.x * 128;
  const int lr = lane & 15, lk = (lane >> 4) * 8;
  const int srow = lane >> 2, scol = (lane & 3) * 8;
  const unsigned short* Ab = A + (size_t)row0 * K;
  const unsigned short* Bb = Bt + (size_t)col0 * K;
  f32x4 acc[4][4] = {};
  for (int k0 = 0; k0 < K; k0 += 32) {
#pragma unroll
    for (int w = 0; w < 2; ++w) {
      int q = wid * 2 + w;  // 16-row chunk
      gload16(&Ab[(size_t)(q * 16 + srow) * K + k0 + scol], &Al[q * 512]);
      gload16(&Bb[(size_t)(q * 16 + srow) * K + k0 + scol], &Bl[q * 512]);
    }
    asm volatile("s_waitcnt vmcnt(0)" ::: "memory");
    __syncthreads();
    bf16x8 af[4], bfv[4];
#pragma unroll
    for (int mm = 0; mm < 4; ++mm)
      af[mm] = *reinterpret_cast<const bf16x8*>(&Al[(wr + mm * 16 + lr) * 32 + lk]);
#pragma unroll
    for (int nn = 0; nn < 4; ++nn)
      bfv[nn] = *reinterpret_cast<const bf16x8*>(&Bl[(wc + nn * 16 + lr) * 32 + lk]);
#pragma unroll
    for (int mm = 0; mm < 4; ++mm)
#pragma unroll
      for (int nn = 0; nn < 4; ++nn)
        acc[mm][nn] = __builtin_amdgcn_mfma_f32_16x16x32_bf16(af[mm], bfv[nn], acc[mm][nn], 0, 0, 0);
    __syncthreads();
  }
  const int rbase = (lane >> 4) * 4;
#pragma unroll
  for (int mm = 0; mm < 4; ++mm) {
#pragma unroll
    for (int nn = 0; nn < 4; ++nn) {
      int c = col0 + wc + nn * 16 + lr;
      int which = c >> 10;
      int d = c & 1023;
      int h = d >> 6, dh = d & 63;
      float bv = bias[c];
      int m0 = row0 + wr + mm * 16 + rbase;
      int b = m0 >> 11, s0 = m0 & 2047;
      if (which == 2) {
        int kt = s0 >> 6, key0 = s0 & 63;
        ushort4 pv;
        pv.x = f2bf(acc[mm][nn][0] + bv);
        pv.y = f2bf(acc[mm][nn][1] + bv);
        pv.z = f2bf(acc[mm][nn][2] + bv);
        pv.w = f2bf(acc[mm][nn][3] + bv);
        *reinterpret_cast<ushort4*>(
            &vtg[(((size_t)(b * 16 + h) * 32 + kt) * 64 + dh) * 64 + key0]) = pv;
      } else {
        unsigned short* dst = (which == 0) ? qw : kw;
#pragma unroll
        for (int r = 0; r < 4; ++r)
          dst[(((size_t)b * 16 + h) * 2048 + (s0 + r)) * 64 + dh] = f2bf(acc[mm][nn][r] + bv);
      }
    }
  }
}

// ---------------- Flash attention: 512 threads / 8 waves, q-tile 128 (16 rows/wave), KV tile 64
__global__ __launch_bounds__(512, 4) void attn_kernel(
    const unsigned short* __restrict__ qw, const unsigned short* __restrict__ kw,
    const unsigned short* __restrict__ vtg, unsigned short* __restrict__ ow) {
  const int S = 2048;
  __shared__ unsigned short QP[9216];  // Ql[128][72] reused as Pl[8][16][72]
  __shared__ unsigned short Kl[64][72];
  __shared__ unsigned short Vt[64][72];  // [dh][key] (pre-transposed in global)
  const int t = threadIdx.x, lane = t & 63, wid = t >> 6;
  const int qt = blockIdx.x, bh = blockIdx.y;
  const int b = bh >> 4, h = bh & 15;
  const unsigned short* Qg = qw + (size_t)bh * S * 64 + (size_t)qt * 128 * 64;
  const unsigned short* Kg = kw + (size_t)bh * S * 64;
  const unsigned short* Vgb = vtg + (size_t)bh * 32 * 4096;
  const int lr = lane & 15, lk = (lane >> 4) * 8;

#pragma unroll
  for (int i = 0; i < 2; ++i) {
    int idx = t + i * 512;
    int r = idx >> 3, c = (idx & 7) << 3;
    *reinterpret_cast<int4*>(&QP[r * 72 + c]) = *reinterpret_cast<const int4*>(&Qg[r * 64 + c]);
  }
  __syncthreads();
  bf16x8 qf[2];
#pragma unroll
  for (int kk = 0; kk < 2; ++kk)
    qf[kk] = *reinterpret_cast<const bf16x8*>(&QP[(wid * 16 + lr) * 72 + kk * 32 + lk]);

  float mrun[4], lrun[4];
  f32x4 o[4] = {};
#pragma unroll
  for (int r = 0; r < 4; ++r) { mrun[r] = -INFINITY; lrun[r] = 0.f; }

  for (int kt = 0; kt < 32; ++kt) {
    const unsigned short* Kt = Kg + (size_t)kt * 4096;
    const unsigned short* Vs = Vgb + (size_t)kt * 4096;
    {
      int r = t >> 3, c = (t & 7) << 3;
      *reinterpret_cast<int4*>(&Kl[r][c]) = *reinterpret_cast<const int4*>(&Kt[r * 64 + c]);
      *reinterpret_cast<int4*>(&Vt[r][c]) = *reinterpret_cast<const int4*>(&Vs[r * 64 + c]);
    }
    __syncthreads();

    // QK^T: sc[kf] holds 4 q-rows x 16 keys each
    f32x4 sc[4];
#pragma unroll
    for (int kf = 0; kf < 4; ++kf) {
      f32x4 s = {0.f, 0.f, 0.f, 0.f};
      s = __builtin_amdgcn_mfma_f32_16x16x32_bf16(
          qf[0], *reinterpret_cast<const bf16x8*>(&Kl[kf * 16 + lr][lk]), s, 0, 0, 0);
      s = __builtin_amdgcn_mfma_f32_16x16x32_bf16(
          qf[1], *reinterpret_cast<const bf16x8*>(&Kl[kf * 16 + lr][32 + lk]), s, 0, 0, 0);
      sc[kf] = s * 0.125f;
    }

    // online softmax: each 16-lane group owns 4 q-rows
#pragma unroll
    for (int r = 0; r < 4; ++r) {
      float tm = fmaxf(fmaxf(sc[0][r], sc[1][r]), fmaxf(sc[2][r], sc[3][r]));
      tm = fmaxf(tm, __shfl_xor(tm, 1));
      tm = fmaxf(tm, __shfl_xor(tm, 2));
      tm = fmaxf(tm, __shfl_xor(tm, 4));
      tm = fmaxf(tm, __shfl_xor(tm, 8));
      float mnew = fmaxf(mrun[r], tm);
      float alpha = exp2f((mrun[r] - mnew) * LOG2E);
      mrun[r] = mnew;
      float ps = 0.f;
#pragma unroll
      for (int kf = 0; kf < 4; ++kf) {
        float p = exp2f((sc[kf][r] - mnew) * LOG2E);
        sc[kf][r] = p;
        ps += p;
      }
      ps += __shfl_xor(ps, 1);
      ps += __shfl_xor(ps, 2);
      ps += __shfl_xor(ps, 4);
      ps += __shfl_xor(ps, 8);
      lrun[r] = lrun[r] * alpha + ps;
#pragma unroll
      for (int n = 0; n < 4; ++n) o[n][r] *= alpha;
    }

    // P -> LDS (A-fragment layout), reusing Q region
#pragma unroll
    for (int kf = 0; kf < 4; ++kf)
#pragma unroll
      for (int r = 0; r < 4; ++r)
        QP[(wid * 16 + (lane >> 4) * 4 + r) * 72 + kf * 16 + lr] = f2bf(sc[kf][r]);
    asm volatile("s_waitcnt lgkmcnt(0)" ::: "memory");
    __builtin_amdgcn_sched_barrier(0);

    // PV
    bf16x8 pf0 = *reinterpret_cast<const bf16x8*>(&QP[(wid * 16 + lr) * 72 + lk]);
    bf16x8 pf1 = *reinterpret_cast<const bf16x8*>(&QP[(wid * 16 + lr) * 72 + 32 + lk]);
#pragma unroll
    for (int n = 0; n < 4; ++n) {
      o[n] = __builtin_amdgcn_mfma_f32_16x16x32_bf16(
          pf0, *reinterpret_cast<const bf16x8*>(&Vt[n * 16 + lr][lk]), o[n], 0, 0, 0);
      o[n] = __builtin_amdgcn_mfma_f32_16x16x32_bf16(
          pf1, *reinterpret_cast<const bf16x8*>(&Vt[n * 16 + lr][32 + lk]), o[n], 0, 0, 0);
    }
    __syncthreads();
  }

  // epilogue: ow layout [b][s][h*64+dh]
#pragma unroll
  for (int n = 0; n < 4; ++n) {
#pragma unroll
    for (int r = 0; r < 4; ++r) {
      int srow = qt * 128 + wid * 16 + (lane >> 4) * 4 + r;
      int dh = n * 16 + lr;
      ow[(((size_t)b * 2048 + srow) * 16 + h) * 64 + dh] = f2bf(o[n][r] / lrun[r]);
    }
  }
}

// ---------------- GEMM2: out = attn_out @ pT^T + b_proj (f32 out)
__global__ __launch_bounds__(256) void gemm_proj_b(
    const unsigned short* __restrict__ A,   // [4096][1024] bf16
    const unsigned short* __restrict__ Bt,  // [1024][1024] bf16
    const float* __restrict__ bias, float* __restrict__ out) {
  const int K = 1024, N = 1024;
  __shared__ unsigned short Al[4096];
  __shared__ unsigned short Bl[4096];
  const int t = threadIdx.x, lane = t & 63, wid = t >> 6;
  const int wr = (wid >> 1) * 64, wc = (wid & 1) * 64;
  const int row0 = blockIdx.y * 128, col0 = blockIdx.x * 128;
  const int lr = lane & 15, lk = (lane >> 4) * 8;
  const int srow = lane >> 2, scol = (lane & 3) * 8;
  const unsigned short* Ab = A + (size_t)row0 * K;
  const unsigned short* Bb = Bt + (size_t)col0 * K;
  f32x4 acc[4][4] = {};
  for (int k0 = 0; k0 < K; k0 += 32) {
#pragma unroll
    for (int w = 0; w < 2; ++w) {
      int q = wid * 2 + w;
      gload16(&Ab[(size_t)(q * 16 + srow) * K + k0 + scol], &Al[q * 512]);
      gload16(&Bb[(size_t)(q * 16 + srow) * K + k0 + scol], &Bl[q * 512]);
    }
    asm volatile("s_waitcnt vmcnt(0)" ::: "memory");
    __syncthreads();
    bf16x8 af[4], bfv[4];
#pragma unroll
    for (int mm = 0; mm < 4; ++mm)
      af[mm] = *reinterpret_cast<const bf16x8*>(&Al[(wr + mm * 16 + lr) * 32 + lk]);
#pragma unroll
    for (int nn = 0; nn < 4; ++nn)
      bfv[nn] = *reinterpret_cast<const bf16x8*>(&Bl[(wc + nn * 16 + lr) * 32 + lk]);
#pragma unroll
    for (int mm = 0; mm < 4; ++mm)
#pragma unroll
      for (int nn = 0; nn < 4; ++nn)
        acc[mm][nn] = __builtin_amdgcn_mfma_f32_16x16x32_bf16(af[mm], bfv[nn], acc[mm][nn], 0, 0, 0);
    __syncthreads();
  }
  const int rbase = (lane >> 4) * 4;
#pragma unroll
  for (int mm = 0; mm < 4; ++mm) {
#pragma unroll
    for (int nn = 0; nn < 4; ++nn) {
      int c = col0 + wc + nn * 16 + lr;
      float bv = bias[c];
#pragma unroll
      for (int r = 0; r < 4; ++r) {
        int m = row0 + wr + mm * 16 + rbase + r;
        out[(size_t)m * N + c] = acc[mm][nn][r] + bv;
      }
    }
  }
}

extern "C" void kernel_launch(void* const* d_in, const int* in_sizes, int n_in,
                              void* d_out, int out_size, void* d_ws, size_t ws_size,
                              hipStream_t stream) {
  const float* hs = (const float*)d_in[0];
  const float* w_attn = (const float*)d_in[1];
  const float* b_attn = (const float*)d_in[2];
  const float* w_proj = (const float*)d_in[3];
  const float* b_proj = (const float*)d_in[4];
  float* out = (float*)d_out;

  const size_t HEAD = (size_t)2 * 16 * 2048 * 64;  // 4,194,304 elems
  unsigned short* qw = (unsigned short*)d_ws;
  unsigned short* kw = qw + HEAD;
  unsigned short* vtg = kw + HEAD;
  unsigned short* hs_b = vtg + HEAD;          // reused as ow after gemm_qkv
  unsigned short* ow = hs_b;
  unsigned short* wT = hs_b + HEAD;           // 3072*1024
  unsigned short* pT = wT + (size_t)3072 * 1024;  // 1024*1024

  cvt_bf16<<<2048, 256, 0, stream>>>(hs, hs_b, 1048576);
  transpose_cvt<<<dim3(48, 16), 256, 0, stream>>>(w_attn, wT, 1024, 3072);
  transpose_cvt<<<dim3(16, 16), 256, 0, stream>>>(w_proj, pT, 1024, 1024);

  gemm_qkv_b<<<dim3(24, 32), 256, 0, stream>>>(hs_b, wT, b_attn, qw, kw, vtg);
  attn_kernel<<<dim3(16, 32), 512, 0, stream>>>(qw, kw, vtg, ow);
  gemm_proj_b<<<dim3(8, 32), 256, 0, stream>>>(ow, pT, b_proj, out);
}

// Round 3
// 160.874 us; speedup vs baseline: 2.2399x; 1.3094x over previous
//
#include <hip/hip_runtime.h>
#include <hip/hip_bf16.h>

typedef __attribute__((ext_vector_type(8))) short bf16x8;
typedef __attribute__((ext_vector_type(4))) float f32x4;
typedef __attribute__((ext_vector_type(16))) float f32x16;

#define LOG2E 1.4426950408889634f

__device__ inline unsigned short f2bf(float f) {
  union { float f; unsigned u; } x; x.f = f;
  unsigned u = x.u;
  unsigned r = u + 0x7FFFu + ((u >> 16) & 1u);
  return (unsigned short)(r >> 16);
}

__device__ inline void gload16(const unsigned short* g, unsigned short* l) {
  __builtin_amdgcn_global_load_lds(
      (const __attribute__((address_space(1))) unsigned int*)g,
      (__attribute__((address_space(3))) unsigned int*)l, 16, 0, 0);
}

// pack 8 consecutive-key P values (f32, swapped-QKT acc layout) into a PV B-fragment.
// Lane holds keys {J..J+3, J+8..J+11} (+4 if lane>=32). cvt_pk pairs then two
// permlane32_swap exchanges assemble keys J..J+7 (lo lanes) / J+8..J+15 (hi lanes).
template <int J>
__device__ inline bf16x8 pack_pfrag(f32x16 p) {
  int X, Y, Z, W;
  asm("v_cvt_pk_bf16_f32 %0, %1, %2" : "=v"(X) : "v"(p[J + 0]), "v"(p[J + 1]));
  asm("v_cvt_pk_bf16_f32 %0, %1, %2" : "=v"(Y) : "v"(p[J + 2]), "v"(p[J + 3]));
  asm("v_cvt_pk_bf16_f32 %0, %1, %2" : "=v"(Z) : "v"(p[J + 4]), "v"(p[J + 5]));
  asm("v_cvt_pk_bf16_f32 %0, %1, %2" : "=v"(W) : "v"(p[J + 6]), "v"(p[J + 7]));
  asm("v_permlane32_swap_b32 %0, %1" : "+v"(X), "+v"(Z));
  asm("v_permlane32_swap_b32 %0, %1" : "+v"(Y), "+v"(W));
  union { int w[4]; bf16x8 v; } u;
  u.w[0] = X; u.w[1] = Y; u.w[2] = Z; u.w[3] = W;
  return u.v;
}

// ---------------- prep: f32 -> bf16 elementwise
__global__ __launch_bounds__(256) void cvt_bf16(const float* __restrict__ X,
                                                unsigned short* __restrict__ Y, int n4) {
  int i = blockIdx.x * blockDim.x + threadIdx.x;
  int stride = gridDim.x * blockDim.x;
  for (; i < n4; i += stride) {
    float4 v = reinterpret_cast<const float4*>(X)[i];
    ushort4 o;
    o.x = f2bf(v.x); o.y = f2bf(v.y); o.z = f2bf(v.z); o.w = f2bf(v.w);
    reinterpret_cast<ushort4*>(Y)[i] = o;
  }
}

// ---------------- prep: W[K][N] f32 -> WT[N][K] bf16 (64x64 tiles via LDS)
__global__ __launch_bounds__(256) void transpose_cvt(const float* __restrict__ W,
                                                     unsigned short* __restrict__ WT,
                                                     int K, int N) {
  __shared__ unsigned short Tl[64][72];
  const int t = threadIdx.x;
  const int n0 = blockIdx.x * 64, k0 = blockIdx.y * 64;
#pragma unroll
  for (int i = 0; i < 4; ++i) {
    int idx = t + i * 256;
    int r = idx >> 4, c4 = (idx & 15) << 2;
    float4 v = *reinterpret_cast<const float4*>(&W[(size_t)(k0 + r) * N + n0 + c4]);
    Tl[c4 + 0][r] = f2bf(v.x);
    Tl[c4 + 1][r] = f2bf(v.y);
    Tl[c4 + 2][r] = f2bf(v.z);
    Tl[c4 + 3][r] = f2bf(v.w);
  }
  __syncthreads();
#pragma unroll
  for (int i = 0; i < 2; ++i) {
    int idx = t + i * 256;
    int rr = idx >> 3, cc = (idx & 7) << 3;
    *reinterpret_cast<int4*>(&WT[(size_t)(n0 + rr) * K + k0 + cc]) =
        *reinterpret_cast<const int4*>(&Tl[rr][cc]);
  }
}

// ---------------- GEMM1: qkv = hs_b @ wT^T + b_attn -> q/k [bh][s][dh], v transposed blocks
__global__ __launch_bounds__(256) void gemm_qkv_b(
    const unsigned short* __restrict__ A, const unsigned short* __restrict__ Bt,
    const float* __restrict__ bias,
    unsigned short* __restrict__ qw, unsigned short* __restrict__ kw,
    unsigned short* __restrict__ vtg) {
  const int K = 1024;
  __shared__ unsigned short Al[4096];
  __shared__ unsigned short Bl[4096];
  const int t = threadIdx.x, lane = t & 63, wid = t >> 6;
  const int wr = (wid >> 1) * 64, wc = (wid & 1) * 64;
  const int row0 = blockIdx.y * 128, col0 = blockIdx.x * 128;
  const int lr = lane & 15, lk = (lane >> 4) * 8;
  const int srow = lane >> 2, scol = (lane & 3) * 8;
  const unsigned short* Ab = A + (size_t)row0 * K;
  const unsigned short* Bb = Bt + (size_t)col0 * K;
  f32x4 acc[4][4] = {};
  for (int k0 = 0; k0 < K; k0 += 32) {
#pragma unroll
    for (int w = 0; w < 2; ++w) {
      int q = wid * 2 + w;
      gload16(&Ab[(size_t)(q * 16 + srow) * K + k0 + scol], &Al[q * 512]);
      gload16(&Bb[(size_t)(q * 16 + srow) * K + k0 + scol], &Bl[q * 512]);
    }
    asm volatile("s_waitcnt vmcnt(0)" ::: "memory");
    __syncthreads();
    bf16x8 af[4], bfv[4];
#pragma unroll
    for (int mm = 0; mm < 4; ++mm)
      af[mm] = *reinterpret_cast<const bf16x8*>(&Al[(wr + mm * 16 + lr) * 32 + lk]);
#pragma unroll
    for (int nn = 0; nn < 4; ++nn)
      bfv[nn] = *reinterpret_cast<const bf16x8*>(&Bl[(wc + nn * 16 + lr) * 32 + lk]);
#pragma unroll
    for (int mm = 0; mm < 4; ++mm)
#pragma unroll
      for (int nn = 0; nn < 4; ++nn)
        acc[mm][nn] = __builtin_amdgcn_mfma_f32_16x16x32_bf16(af[mm], bfv[nn], acc[mm][nn], 0, 0, 0);
    __syncthreads();
  }
  const int rbase = (lane >> 4) * 4;
#pragma unroll
  for (int mm = 0; mm < 4; ++mm) {
#pragma unroll
    for (int nn = 0; nn < 4; ++nn) {
      int c = col0 + wc + nn * 16 + lr;
      int which = c >> 10;
      int d = c & 1023;
      int h = d >> 6, dh = d & 63;
      float bv = bias[c];
      int m0 = row0 + wr + mm * 16 + rbase;
      int b = m0 >> 11, s0 = m0 & 2047;
      if (which == 2) {
        int kt = s0 >> 6, key0 = s0 & 63;
        ushort4 pv;
        pv.x = f2bf(acc[mm][nn][0] + bv);
        pv.y = f2bf(acc[mm][nn][1] + bv);
        pv.z = f2bf(acc[mm][nn][2] + bv);
        pv.w = f2bf(acc[mm][nn][3] + bv);
        *reinterpret_cast<ushort4*>(
            &vtg[(((size_t)(b * 16 + h) * 32 + kt) * 64 + dh) * 64 + key0]) = pv;
      } else {
        unsigned short* dst = (which == 0) ? qw : kw;
#pragma unroll
        for (int r = 0; r < 4; ++r)
          dst[(((size_t)b * 16 + h) * 2048 + (s0 + r)) * 64 + dh] = f2bf(acc[mm][nn][r] + bv);
      }
    }
  }
}

// ---------------- Flash attention: 4 waves x 32 q-rows, swapped-QKT 32x32, KV tile 64
__global__ __launch_bounds__(256) void attn_kernel(
    const unsigned short* __restrict__ qw, const unsigned short* __restrict__ kw,
    const unsigned short* __restrict__ vtg, unsigned short* __restrict__ ow) {
  // LDS: [buf][ {K tile [key][d], V tile [dh][key]} ], each 64x64 bf16, XOR-swizzled:
  // logical (row, colgroup g of 8 ushorts) stored at colgroup g ^ (row & 7).
  __shared__ unsigned short KV[16384];  // 32 KB: 2 bufs x (K 4096 + V 4096)
  const int t = threadIdx.x, lane = t & 63, wid = t >> 6;
  const int l31 = lane & 31, hi = lane >> 5;
  const int qt = blockIdx.x, bh = blockIdx.y;
  const int b = bh >> 4, h = bh & 15;
  const unsigned short* Qg = qw + (size_t)bh * 2048 * 64;
  const unsigned short* Kg = kw + (size_t)bh * 2048 * 64;
  const unsigned short* Vg = vtg + (size_t)bh * 32 * 4096;
  const int q0 = qt * 128 + wid * 32;
  const float F = 0.125f * LOG2E;

  // Q fragments (B-operand): lane needs Q[q0+l31][kc*16 + hi*8 .. +7]
  bf16x8 qf[4];
#pragma unroll
  for (int kc = 0; kc < 4; ++kc)
    qf[kc] = *reinterpret_cast<const bf16x8*>(&Qg[(q0 + l31) * 64 + kc * 16 + hi * 8]);

  f32x16 oA = {0,0,0,0,0,0,0,0,0,0,0,0,0,0,0,0};
  f32x16 oB = {0,0,0,0,0,0,0,0,0,0,0,0,0,0,0,0};
  float mrun = -INFINITY, lrun = 0.f;

  // staging: thread covers slots {wid*2, wid*2+1} x 64 lanes; LDS linear, global pre-swizzled
  const int srow_lo = lane >> 3;          // row offset within 8-row chunk
  const int scg = (lane & 7) ^ srow_lo;   // logical colgroup for this lane's slot

#define STAGE(buf, kt)                                                              \
  {                                                                                 \
    const unsigned short* Kt = Kg + (size_t)(kt) * 4096;                            \
    const unsigned short* Vs = Vg + (size_t)(kt) * 4096;                            \
    unsigned short* Kl = KV + (buf) * 8192;                                         \
    unsigned short* Vl = KV + (buf) * 8192 + 4096;                                  \
    _Pragma("unroll") for (int i = 0; i < 2; ++i) {                                 \
      int chunk = wid * 2 + i;                                                      \
      int row = chunk * 8 + srow_lo;                                                \
      gload16(&Kt[row * 64 + scg * 8], &Kl[chunk * 512]);                           \
      gload16(&Vs[row * 64 + scg * 8], &Vl[chunk * 512]);                           \
    }                                                                               \
  }

  STAGE(0, 0)

  for (int kt = 0; kt < 32; ++kt) {
    const int cur = kt & 1;
    if (kt + 1 < 32) {
      STAGE(cur ^ 1, kt + 1)
      asm volatile("s_waitcnt vmcnt(4)" ::: "memory");
    } else {
      asm volatile("s_waitcnt vmcnt(0)" ::: "memory");
    }
    __builtin_amdgcn_s_barrier();
    const unsigned short* Kl = KV + cur * 8192;
    const unsigned short* Vl = KV + cur * 8192 + 4096;

    // S^T = K @ Q^T : keys 0-31 -> sA, keys 32-63 -> sB
    f32x16 sA = {0,0,0,0,0,0,0,0,0,0,0,0,0,0,0,0};
    f32x16 sB = {0,0,0,0,0,0,0,0,0,0,0,0,0,0,0,0};
#pragma unroll
    for (int kc = 0; kc < 4; ++kc) {
      bf16x8 k0f = *reinterpret_cast<const bf16x8*>(
          &Kl[l31 * 64 + (((kc * 2 + hi) ^ (l31 & 7)) << 3)]);
      bf16x8 k1f = *reinterpret_cast<const bf16x8*>(
          &Kl[(32 + l31) * 64 + (((kc * 2 + hi) ^ (l31 & 7)) << 3)]);
      sA = __builtin_amdgcn_mfma_f32_32x32x16_bf16(k0f, qf[kc], sA, 0, 0, 0);
      sB = __builtin_amdgcn_mfma_f32_32x32x16_bf16(k1f, qf[kc], sB, 0, 0, 0);
    }

    // online softmax in raw-score space; scale folded into exp (factor F)
    float pmax = sA[0];
#pragma unroll
    for (int j = 1; j < 16; ++j) pmax = fmaxf(pmax, sA[j]);
#pragma unroll
    for (int j = 0; j < 16; ++j) pmax = fmaxf(pmax, sB[j]);
    pmax = fmaxf(pmax, __shfl_xor(pmax, 32));
    float mnew = fmaxf(mrun, pmax);
    float alpha = exp2f((mrun - mnew) * F);
    mrun = mnew;
    float mF = mnew * F;
    float rs = 0.f;
#pragma unroll
    for (int j = 0; j < 16; ++j) {
      float p = exp2f(sA[j] * F - mF);
      sA[j] = p; rs += p;
    }
#pragma unroll
    for (int j = 0; j < 16; ++j) {
      float p = exp2f(sB[j] * F - mF);
      sB[j] = p; rs += p;
    }
    rs += __shfl_xor(rs, 32);
    lrun = lrun * alpha + rs;
    oA *= alpha;
    oB *= alpha;

    // P fragments for PV (B-operand, keys chunks of 16)
    bf16x8 pf0 = pack_pfrag<0>(sA);
    bf16x8 pf1 = pack_pfrag<8>(sA);
    bf16x8 pf2 = pack_pfrag<0>(sB);
    bf16x8 pf3 = pack_pfrag<8>(sB);

    // O^T += V^T @ P^T : dh 0-31 -> oA, dh 32-63 -> oB
#pragma unroll
    for (int c = 0; c < 4; ++c) {
      bf16x8 pf = (c == 0) ? pf0 : (c == 1) ? pf1 : (c == 2) ? pf2 : pf3;
      int g = c * 2 + hi;  // key colgroup
      bf16x8 v0f = *reinterpret_cast<const bf16x8*>(
          &Vl[l31 * 64 + ((g ^ (l31 & 7)) << 3)]);
      bf16x8 v1f = *reinterpret_cast<const bf16x8*>(
          &Vl[(32 + l31) * 64 + ((g ^ (l31 & 7)) << 3)]);
      oA = __builtin_amdgcn_mfma_f32_32x32x16_bf16(v0f, pf, oA, 0, 0, 0);
      oB = __builtin_amdgcn_mfma_f32_32x32x16_bf16(v1f, pf, oB, 0, 0, 0);
    }
    __builtin_amdgcn_s_barrier();
  }
#undef STAGE

  // epilogue: lane owns q-row q0+l31; O^T regs: dh = d*32 + (j&3)+8*(j>>2)+4*hi
  float inv = 1.0f / lrun;
  const int qg = q0 + l31;
  unsigned short* orow = ow + (((size_t)b * 2048 + qg) * 16 + h) * 64;
#pragma unroll
  for (int j = 0; j < 16; ++j) {
    int dh = (j & 3) + 8 * (j >> 2) + 4 * hi;
    orow[dh] = f2bf(oA[j] * inv);
    orow[32 + dh] = f2bf(oB[j] * inv);
  }
}

// ---------------- GEMM2: out = attn_out @ pT^T + b_proj (f32 out)
__global__ __launch_bounds__(256) void gemm_proj_b(
    const unsigned short* __restrict__ A, const unsigned short* __restrict__ Bt,
    const float* __restrict__ bias, float* __restrict__ out) {
  const int K = 1024, N = 1024;
  __shared__ unsigned short Al[4096];
  __shared__ unsigned short Bl[4096];
  const int t = threadIdx.x, lane = t & 63, wid = t >> 6;
  const int wr = (wid >> 1) * 64, wc = (wid & 1) * 64;
  const int row0 = blockIdx.y * 128, col0 = blockIdx.x * 128;
  const int lr = lane & 15, lk = (lane >> 4) * 8;
  const int srow = lane >> 2, scol = (lane & 3) * 8;
  const unsigned short* Ab = A + (size_t)row0 * K;
  const unsigned short* Bb = Bt + (size_t)col0 * K;
  f32x4 acc[4][4] = {};
  for (int k0 = 0; k0 < K; k0 += 32) {
#pragma unroll
    for (int w = 0; w < 2; ++w) {
      int q = wid * 2 + w;
      gload16(&Ab[(size_t)(q * 16 + srow) * K + k0 + scol], &Al[q * 512]);
      gload16(&Bb[(size_t)(q * 16 + srow) * K + k0 + scol], &Bl[q * 512]);
    }
    asm volatile("s_waitcnt vmcnt(0)" ::: "memory");
    __syncthreads();
    bf16x8 af[4], bfv[4];
#pragma unroll
    for (int mm = 0; mm < 4; ++mm)
      af[mm] = *reinterpret_cast<const bf16x8*>(&Al[(wr + mm * 16 + lr) * 32 + lk]);
#pragma unroll
    for (int nn = 0; nn < 4; ++nn)
      bfv[nn] = *reinterpret_cast<const bf16x8*>(&Bl[(wc + nn * 16 + lr) * 32 + lk]);
#pragma unroll
    for (int mm = 0; mm < 4; ++mm)
#pragma unroll
      for (int nn = 0; nn < 4; ++nn)
        acc[mm][nn] = __builtin_amdgcn_mfma_f32_16x16x32_bf16(af[mm], bfv[nn], acc[mm][nn], 0, 0, 0);
    __syncthreads();
  }
  const int rbase = (lane >> 4) * 4;
#pragma unroll
  for (int mm = 0; mm < 4; ++mm) {
#pragma unroll
    for (int nn = 0; nn < 4; ++nn) {
      int c = col0 + wc + nn * 16 + lr;
      float bv = bias[c];
#pragma unroll
      for (int r = 0; r < 4; ++r) {
        int m = row0 + wr + mm * 16 + rbase + r;
        out[(size_t)m * N + c] = acc[mm][nn][r] + bv;
      }
    }
  }
}

extern "C" void kernel_launch(void* const* d_in, const int* in_sizes, int n_in,
                              void* d_out, int out_size, void* d_ws, size_t ws_size,
                              hipStream_t stream) {
  const float* hs = (const float*)d_in[0];
  const float* w_attn = (const float*)d_in[1];
  const float* b_attn = (const float*)d_in[2];
  const float* w_proj = (const float*)d_in[3];
  const float* b_proj = (const float*)d_in[4];
  float* out = (float*)d_out;

  const size_t HEAD = (size_t)2 * 16 * 2048 * 64;
  unsigned short* qw = (unsigned short*)d_ws;
  unsigned short* kw = qw + HEAD;
  unsigned short* vtg = kw + HEAD;
  unsigned short* hs_b = vtg + HEAD;
  unsigned short* ow = hs_b;
  unsigned short* wT = hs_b + HEAD;
  unsigned short* pT = wT + (size_t)3072 * 1024;

  cvt_bf16<<<2048, 256, 0, stream>>>(hs, hs_b, 1048576);
  transpose_cvt<<<dim3(48, 16), 256, 0, stream>>>(w_attn, wT, 1024, 3072);
  transpose_cvt<<<dim3(16, 16), 256, 0, stream>>>(w_proj, pT, 1024, 1024);

  gemm_qkv_b<<<dim3(24, 32), 256, 0, stream>>>(hs_b, wT, b_attn, qw, kw, vtg);
  attn_kernel<<<dim3(16, 32), 256, 0, stream>>>(qw, kw, vtg, ow);
  gemm_proj_b<<<dim3(8, 32), 256, 0, stream>>>(ow, pT, b_proj, out);
}

// Round 4
// 151.657 us; speedup vs baseline: 2.3760x; 1.0608x over previous
//
#include <hip/hip_runtime.h>
#include <hip/hip_bf16.h>

typedef __attribute__((ext_vector_type(8))) short bf16x8;
typedef __attribute__((ext_vector_type(4))) float f32x4;
typedef __attribute__((ext_vector_type(16))) float f32x16;

#define LOG2E 1.4426950408889634f

__device__ inline unsigned short f2bf(float f) {
  union { float f; unsigned u; } x; x.f = f;
  unsigned u = x.u;
  unsigned r = u + 0x7FFFu + ((u >> 16) & 1u);
  return (unsigned short)(r >> 16);
}

__device__ inline void gload16(const unsigned short* g, unsigned short* l) {
  __builtin_amdgcn_global_load_lds(
      (const __attribute__((address_space(1))) unsigned int*)g,
      (__attribute__((address_space(3))) unsigned int*)l, 16, 0, 0);
}

// pack 8 consecutive-key P values (f32, swapped-QKT acc layout) into a PV B-fragment.
template <int J>
__device__ inline bf16x8 pack_pfrag(f32x16 p) {
  int X, Y, Z, W;
  asm("v_cvt_pk_bf16_f32 %0, %1, %2" : "=v"(X) : "v"(p[J + 0]), "v"(p[J + 1]));
  asm("v_cvt_pk_bf16_f32 %0, %1, %2" : "=v"(Y) : "v"(p[J + 2]), "v"(p[J + 3]));
  asm("v_cvt_pk_bf16_f32 %0, %1, %2" : "=v"(Z) : "v"(p[J + 4]), "v"(p[J + 5]));
  asm("v_cvt_pk_bf16_f32 %0, %1, %2" : "=v"(W) : "v"(p[J + 6]), "v"(p[J + 7]));
  asm("v_permlane32_swap_b32 %0, %1" : "+v"(X), "+v"(Z));
  asm("v_permlane32_swap_b32 %0, %1" : "+v"(Y), "+v"(W));
  union { int w[4]; bf16x8 v; } u;
  u.w[0] = X; u.w[1] = Y; u.w[2] = Z; u.w[3] = W;
  return u.v;
}

// ---------------- prep: f32 -> bf16 elementwise
__global__ __launch_bounds__(256) void cvt_bf16(const float* __restrict__ X,
                                                unsigned short* __restrict__ Y, int n4) {
  int i = blockIdx.x * blockDim.x + threadIdx.x;
  int stride = gridDim.x * blockDim.x;
  for (; i < n4; i += stride) {
    float4 v = reinterpret_cast<const float4*>(X)[i];
    ushort4 o;
    o.x = f2bf(v.x); o.y = f2bf(v.y); o.z = f2bf(v.z); o.w = f2bf(v.w);
    reinterpret_cast<ushort4*>(Y)[i] = o;
  }
}

// ---------------- prep: W[K][N] f32 -> WT[N][K] bf16 (64x64 tiles via LDS)
__global__ __launch_bounds__(256) void transpose_cvt(const float* __restrict__ W,
                                                     unsigned short* __restrict__ WT,
                                                     int K, int N) {
  __shared__ unsigned short Tl[64][72];
  const int t = threadIdx.x;
  const int n0 = blockIdx.x * 64, k0 = blockIdx.y * 64;
#pragma unroll
  for (int i = 0; i < 4; ++i) {
    int idx = t + i * 256;
    int r = idx >> 4, c4 = (idx & 15) << 2;
    float4 v = *reinterpret_cast<const float4*>(&W[(size_t)(k0 + r) * N + n0 + c4]);
    Tl[c4 + 0][r] = f2bf(v.x);
    Tl[c4 + 1][r] = f2bf(v.y);
    Tl[c4 + 2][r] = f2bf(v.z);
    Tl[c4 + 3][r] = f2bf(v.w);
  }
  __syncthreads();
#pragma unroll
  for (int i = 0; i < 2; ++i) {
    int idx = t + i * 256;
    int rr = idx >> 3, cc = (idx & 7) << 3;
    *reinterpret_cast<int4*>(&WT[(size_t)(n0 + rr) * K + k0 + cc]) =
        *reinterpret_cast<const int4*>(&Tl[rr][cc]);
  }
}

// ---------------- GEMM1: qkv = hs_b @ wT^T + b_attn -> q/k [bh][s][dh], v transposed blocks
__global__ __launch_bounds__(256) void gemm_qkv_b(
    const unsigned short* __restrict__ A, const unsigned short* __restrict__ Bt,
    const float* __restrict__ bias,
    unsigned short* __restrict__ qw, unsigned short* __restrict__ kw,
    unsigned short* __restrict__ vtg) {
  const int K = 1024;
  __shared__ unsigned short Al[4096];
  __shared__ unsigned short Bl[4096];
  const int t = threadIdx.x, lane = t & 63, wid = t >> 6;
  const int wr = (wid >> 1) * 64, wc = (wid & 1) * 64;
  const int row0 = blockIdx.y * 128, col0 = blockIdx.x * 128;
  const int lr = lane & 15, lk = (lane >> 4) * 8;
  const int srow = lane >> 2, scol = (lane & 3) * 8;
  const unsigned short* Ab = A + (size_t)row0 * K;
  const unsigned short* Bb = Bt + (size_t)col0 * K;
  f32x4 acc[4][4] = {};
  for (int k0 = 0; k0 < K; k0 += 32) {
#pragma unroll
    for (int w = 0; w < 2; ++w) {
      int q = wid * 2 + w;
      gload16(&Ab[(size_t)(q * 16 + srow) * K + k0 + scol], &Al[q * 512]);
      gload16(&Bb[(size_t)(q * 16 + srow) * K + k0 + scol], &Bl[q * 512]);
    }
    asm volatile("s_waitcnt vmcnt(0)" ::: "memory");
    __syncthreads();
    bf16x8 af[4], bfv[4];
#pragma unroll
    for (int mm = 0; mm < 4; ++mm)
      af[mm] = *reinterpret_cast<const bf16x8*>(&Al[(wr + mm * 16 + lr) * 32 + lk]);
#pragma unroll
    for (int nn = 0; nn < 4; ++nn)
      bfv[nn] = *reinterpret_cast<const bf16x8*>(&Bl[(wc + nn * 16 + lr) * 32 + lk]);
#pragma unroll
    for (int mm = 0; mm < 4; ++mm)
#pragma unroll
      for (int nn = 0; nn < 4; ++nn)
        acc[mm][nn] = __builtin_amdgcn_mfma_f32_16x16x32_bf16(af[mm], bfv[nn], acc[mm][nn], 0, 0, 0);
    __syncthreads();
  }
  const int rbase = (lane >> 4) * 4;
#pragma unroll
  for (int mm = 0; mm < 4; ++mm) {
#pragma unroll
    for (int nn = 0; nn < 4; ++nn) {
      int c = col0 + wc + nn * 16 + lr;
      int which = c >> 10;
      int d = c & 1023;
      int h = d >> 6, dh = d & 63;
      float bv = bias[c];
      int m0 = row0 + wr + mm * 16 + rbase;
      int b = m0 >> 11, s0 = m0 & 2047;
      if (which == 2) {
        int kt = s0 >> 6, key0 = s0 & 63;
        ushort4 pv;
        pv.x = f2bf(acc[mm][nn][0] + bv);
        pv.y = f2bf(acc[mm][nn][1] + bv);
        pv.z = f2bf(acc[mm][nn][2] + bv);
        pv.w = f2bf(acc[mm][nn][3] + bv);
        *reinterpret_cast<ushort4*>(
            &vtg[(((size_t)(b * 16 + h) * 32 + kt) * 64 + dh) * 64 + key0]) = pv;
      } else {
        unsigned short* dst = (which == 0) ? qw : kw;
#pragma unroll
        for (int r = 0; r < 4; ++r)
          dst[(((size_t)b * 16 + h) * 2048 + (s0 + r)) * 64 + dh] = f2bf(acc[mm][nn][r] + bv);
      }
    }
  }
}

// ---------------- Flash attention: 8 waves = 4 q-subtiles x 2 key-halves (in-block K-split)
__global__ __launch_bounds__(512, 4) void attn_kernel(
    const unsigned short* __restrict__ qw, const unsigned short* __restrict__ kw,
    const unsigned short* __restrict__ vtg, unsigned short* __restrict__ ow) {
  // smem: [half][buf][K 64x64 | V 64x64] bf16, XOR-swizzled = 64 KB;
  // reused after the loop as float EX[4][64][37] (37.9 KB) for half-merge.
  __shared__ char smem[65536];
  unsigned short* KV = (unsigned short*)smem;
  float* EX = (float*)smem;
  const int t = threadIdx.x, lane = t & 63, wid = t >> 6;
  const int half = wid >> 2, wq = wid & 3;
  const int l31 = lane & 31, hi = lane >> 5;
  const int qt = blockIdx.x, bh = blockIdx.y;
  const int b = bh >> 4, h = bh & 15;
  const unsigned short* Qg = qw + (size_t)bh * 2048 * 64;
  const unsigned short* Kg = kw + (size_t)bh * 2048 * 64;
  const unsigned short* Vg = vtg + (size_t)bh * 32 * 4096;
  const int q0 = qt * 128 + wq * 32;
  const float F = 0.125f * LOG2E;

  // Q fragments (B-operand): lane needs Q[q0+l31][kc*16 + hi*8 .. +7]
  bf16x8 qf[4];
#pragma unroll
  for (int kc = 0; kc < 4; ++kc)
    qf[kc] = *reinterpret_cast<const bf16x8*>(&Qg[(q0 + l31) * 64 + kc * 16 + hi * 8]);

  f32x16 oA = {0,0,0,0,0,0,0,0,0,0,0,0,0,0,0,0};
  f32x16 oB = {0,0,0,0,0,0,0,0,0,0,0,0,0,0,0,0};
  float mrun = -INFINITY, lrun = 0.f;

  const int srow_lo = lane >> 3;
  const int scg = (lane & 7) ^ srow_lo;

#define STAGE(buf, kt)                                                              \
  {                                                                                 \
    const unsigned short* Kt = Kg + (size_t)(kt) * 4096;                            \
    const unsigned short* Vs = Vg + (size_t)(kt) * 4096;                            \
    unsigned short* Kl = KV + half * 16384 + (buf) * 8192;                          \
    unsigned short* Vl = Kl + 4096;                                                 \
    _Pragma("unroll") for (int i = 0; i < 2; ++i) {                                 \
      int chunk = wq * 2 + i;                                                       \
      int row = chunk * 8 + srow_lo;                                                \
      gload16(&Kt[row * 64 + scg * 8], &Kl[chunk * 512]);                           \
      gload16(&Vs[row * 64 + scg * 8], &Vl[chunk * 512]);                           \
    }                                                                               \
  }

  const int kt0 = half * 16;
  STAGE(0, kt0)

  for (int it = 0; it < 16; ++it) {
    const int cur = it & 1;
    if (it + 1 < 16) {
      STAGE(cur ^ 1, kt0 + it + 1)
      asm volatile("s_waitcnt vmcnt(4)" ::: "memory");
    } else {
      asm volatile("s_waitcnt vmcnt(0)" ::: "memory");
    }
    __builtin_amdgcn_s_barrier();
    const unsigned short* Kl = KV + half * 16384 + cur * 8192;
    const unsigned short* Vl = Kl + 4096;

    // S^T = K @ Q^T : keys 0-31 -> sA, keys 32-63 -> sB
    f32x16 sA = {0,0,0,0,0,0,0,0,0,0,0,0,0,0,0,0};
    f32x16 sB = {0,0,0,0,0,0,0,0,0,0,0,0,0,0,0,0};
    __builtin_amdgcn_s_setprio(1);
#pragma unroll
    for (int kc = 0; kc < 4; ++kc) {
      bf16x8 k0f = *reinterpret_cast<const bf16x8*>(
          &Kl[l31 * 64 + (((kc * 2 + hi) ^ (l31 & 7)) << 3)]);
      bf16x8 k1f = *reinterpret_cast<const bf16x8*>(
          &Kl[(32 + l31) * 64 + (((kc * 2 + hi) ^ (l31 & 7)) << 3)]);
      sA = __builtin_amdgcn_mfma_f32_32x32x16_bf16(k0f, qf[kc], sA, 0, 0, 0);
      sB = __builtin_amdgcn_mfma_f32_32x32x16_bf16(k1f, qf[kc], sB, 0, 0, 0);
    }
    __builtin_amdgcn_s_setprio(0);

    // tile max via pairwise tree (clang fuses into v_max3 where possible)
    float tmx[16];
#pragma unroll
    for (int j = 0; j < 16; ++j) tmx[j] = fmaxf(sA[j], sB[j]);
#pragma unroll
    for (int s = 8; s >= 1; s >>= 1)
#pragma unroll
      for (int j = 0; j < s; ++j) tmx[j] = fmaxf(tmx[j], tmx[j + s]);
    float pmax = fmaxf(tmx[0], __shfl_xor(tmx[0], 32));

    // defer-max (T13): skip rescale when no lane's max grew past mrun + 44 (~2^8 in P)
    if (!__all(pmax - mrun <= 44.0f)) {
      float mnew = fmaxf(mrun, pmax);
      float alpha = exp2f((mrun - mnew) * F);
      mrun = mnew;
      lrun *= alpha;
      oA *= alpha;
      oB *= alpha;
    }
    float mF = mrun * F;

    float rsv[16];
#pragma unroll
    for (int j = 0; j < 16; ++j) {
      float pa = exp2f(sA[j] * F - mF);
      float pb = exp2f(sB[j] * F - mF);
      sA[j] = pa; sB[j] = pb;
      rsv[j] = pa + pb;
    }
#pragma unroll
    for (int s = 8; s >= 1; s >>= 1)
#pragma unroll
      for (int j = 0; j < s; ++j) rsv[j] += rsv[j + s];
    float rs = rsv[0] + __shfl_xor(rsv[0], 32);
    lrun += rs;

    // P fragments for PV (B-operand, key chunks of 16)
    bf16x8 pf0 = pack_pfrag<0>(sA);
    bf16x8 pf1 = pack_pfrag<8>(sA);
    bf16x8 pf2 = pack_pfrag<0>(sB);
    bf16x8 pf3 = pack_pfrag<8>(sB);

    // O^T += V^T @ P^T : dh 0-31 -> oA, dh 32-63 -> oB
    __builtin_amdgcn_s_setprio(1);
#pragma unroll
    for (int c = 0; c < 4; ++c) {
      bf16x8 pf = (c == 0) ? pf0 : (c == 1) ? pf1 : (c == 2) ? pf2 : pf3;
      int g = c * 2 + hi;
      bf16x8 v0f = *reinterpret_cast<const bf16x8*>(
          &Vl[l31 * 64 + ((g ^ (l31 & 7)) << 3)]);
      bf16x8 v1f = *reinterpret_cast<const bf16x8*>(
          &Vl[(32 + l31) * 64 + ((g ^ (l31 & 7)) << 3)]);
      oA = __builtin_amdgcn_mfma_f32_32x32x16_bf16(v0f, pf, oA, 0, 0, 0);
      oB = __builtin_amdgcn_mfma_f32_32x32x16_bf16(v1f, pf, oB, 0, 0, 0);
    }
    __builtin_amdgcn_s_setprio(0);
    __builtin_amdgcn_s_barrier();
  }
#undef STAGE

  // half-merge: waves 4-7 publish partials; waves 0-3 combine + write
  if (half == 1) {
    float* e = EX + ((size_t)(wq * 64 + lane)) * 37;
#pragma unroll
    for (int j = 0; j < 16; ++j) { e[j] = oA[j]; e[16 + j] = oB[j]; }
    e[32] = mrun; e[33] = lrun;
  }
  __syncthreads();
  if (half == 0) {
    const float* e = EX + ((size_t)(wq * 64 + lane)) * 37;
    float m2 = e[32], l2 = e[33];
    float mstar = fmaxf(mrun, m2);
    float a1 = exp2f((mrun - mstar) * F);
    float a2 = exp2f((m2 - mstar) * F);
    float linv = 1.0f / (lrun * a1 + l2 * a2);
    float c1 = a1 * linv, c2 = a2 * linv;
    const int qg = q0 + l31;
    unsigned short* orow = ow + (((size_t)b * 2048 + qg) * 16 + h) * 64;
#pragma unroll
    for (int j = 0; j < 16; ++j) {
      int dh = (j & 3) + 8 * (j >> 2) + 4 * hi;
      orow[dh] = f2bf(oA[j] * c1 + e[j] * c2);
      orow[32 + dh] = f2bf(oB[j] * c1 + e[16 + j] * c2);
    }
  }
}

// ---------------- GEMM2: out = attn_out @ pT^T + b_proj (f32 out)
__global__ __launch_bounds__(256) void gemm_proj_b(
    const unsigned short* __restrict__ A, const unsigned short* __restrict__ Bt,
    const float* __restrict__ bias, float* __restrict__ out) {
  const int K = 1024, N = 1024;
  __shared__ unsigned short Al[4096];
  __shared__ unsigned short Bl[4096];
  const int t = threadIdx.x, lane = t & 63, wid = t >> 6;
  const int wr = (wid >> 1) * 64, wc = (wid & 1) * 64;
  const int row0 = blockIdx.y * 128, col0 = blockIdx.x * 128;
  const int lr = lane & 15, lk = (lane >> 4) * 8;
  const int srow = lane >> 2, scol = (lane & 3) * 8;
  const unsigned short* Ab = A + (size_t)row0 * K;
  const unsigned short* Bb = Bt + (size_t)col0 * K;
  f32x4 acc[4][4] = {};
  for (int k0 = 0; k0 < K; k0 += 32) {
#pragma unroll
    for (int w = 0; w < 2; ++w) {
      int q = wid * 2 + w;
      gload16(&Ab[(size_t)(q * 16 + srow) * K + k0 + scol], &Al[q * 512]);
      gload16(&Bb[(size_t)(q * 16 + srow) * K + k0 + scol], &Bl[q * 512]);
    }
    asm volatile("s_waitcnt vmcnt(0)" ::: "memory");
    __syncthreads();
    bf16x8 af[4], bfv[4];
#pragma unroll
    for (int mm = 0; mm < 4; ++mm)
      af[mm] = *reinterpret_cast<const bf16x8*>(&Al[(wr + mm * 16 + lr) * 32 + lk]);
#pragma unroll
    for (int nn = 0; nn < 4; ++nn)
      bfv[nn] = *reinterpret_cast<const bf16x8*>(&Bl[(wc + nn * 16 + lr) * 32 + lk]);
#pragma unroll
    for (int mm = 0; mm < 4; ++mm)
#pragma unroll
      for (int nn = 0; nn < 4; ++nn)
        acc[mm][nn] = __builtin_amdgcn_mfma_f32_16x16x32_bf16(af[mm], bfv[nn], acc[mm][nn], 0, 0, 0);
    __syncthreads();
  }
  const int rbase = (lane >> 4) * 4;
#pragma unroll
  for (int mm = 0; mm < 4; ++mm) {
#pragma unroll
    for (int nn = 0; nn < 4; ++nn) {
      int c = col0 + wc + nn * 16 + lr;
      float bv = bias[c];
#pragma unroll
      for (int r = 0; r < 4; ++r) {
        int m = row0 + wr + mm * 16 + rbase + r;
        out[(size_t)m * N + c] = acc[mm][nn][r] + bv;
      }
    }
  }
}

extern "C" void kernel_launch(void* const* d_in, const int* in_sizes, int n_in,
                              void* d_out, int out_size, void* d_ws, size_t ws_size,
                              hipStream_t stream) {
  const float* hs = (const float*)d_in[0];
  const float* w_attn = (const float*)d_in[1];
  const float* b_attn = (const float*)d_in[2];
  const float* w_proj = (const float*)d_in[3];
  const float* b_proj = (const float*)d_in[4];
  float* out = (float*)d_out;

  const size_t HEAD = (size_t)2 * 16 * 2048 * 64;
  unsigned short* qw = (unsigned short*)d_ws;
  unsigned short* kw = qw + HEAD;
  unsigned short* vtg = kw + HEAD;
  unsigned short* hs_b = vtg + HEAD;
  unsigned short* ow = hs_b;
  unsigned short* wT = hs_b + HEAD;
  unsigned short* pT = wT + (size_t)3072 * 1024;

  cvt_bf16<<<2048, 256, 0, stream>>>(hs, hs_b, 1048576);
  transpose_cvt<<<dim3(48, 16), 256, 0, stream>>>(w_attn, wT, 1024, 3072);
  transpose_cvt<<<dim3(16, 16), 256, 0, stream>>>(w_proj, pT, 1024, 1024);

  gemm_qkv_b<<<dim3(24, 32), 256, 0, stream>>>(hs_b, wT, b_attn, qw, kw, vtg);
  attn_kernel<<<dim3(16, 32), 512, 0, stream>>>(qw, kw, vtg, ow);
  gemm_proj_b<<<dim3(8, 32), 256, 0, stream>>>(ow, pT, b_proj, out);
}

// Round 5
// 146.881 us; speedup vs baseline: 2.4533x; 1.0325x over previous
//
#include <hip/hip_runtime.h>
#include <hip/hip_bf16.h>

typedef __attribute__((ext_vector_type(8))) short bf16x8;
typedef __attribute__((ext_vector_type(4))) float f32x4;
typedef __attribute__((ext_vector_type(16))) float f32x16;

#define LOG2E 1.4426950408889634f

__device__ inline unsigned short f2bf(float f) {
  union { float f; unsigned u; } x; x.f = f;
  unsigned u = x.u;
  unsigned r = u + 0x7FFFu + ((u >> 16) & 1u);
  return (unsigned short)(r >> 16);
}

__device__ inline unsigned cvtpk(float lo, float hi) {
  unsigned r;
  asm("v_cvt_pk_bf16_f32 %0, %1, %2" : "=v"(r) : "v"(lo), "v"(hi));
  return r;
}

__device__ inline float max3f(float a, float b, float c) {
  float d;
  asm("v_max3_f32 %0, %1, %2, %3" : "=v"(d) : "v"(a), "v"(b), "v"(c));
  return d;
}

__device__ inline void gload16(const unsigned short* g, unsigned short* l) {
  __builtin_amdgcn_global_load_lds(
      (const __attribute__((address_space(1))) unsigned int*)g,
      (__attribute__((address_space(3))) unsigned int*)l, 16, 0, 0);
}

// pack 8 consecutive-key P values (f32, swapped-QKT acc layout) into a PV B-fragment.
template <int J>
__device__ inline bf16x8 pack_pfrag(f32x16 p) {
  int X, Y, Z, W;
  asm("v_cvt_pk_bf16_f32 %0, %1, %2" : "=v"(X) : "v"(p[J + 0]), "v"(p[J + 1]));
  asm("v_cvt_pk_bf16_f32 %0, %1, %2" : "=v"(Y) : "v"(p[J + 2]), "v"(p[J + 3]));
  asm("v_cvt_pk_bf16_f32 %0, %1, %2" : "=v"(Z) : "v"(p[J + 4]), "v"(p[J + 5]));
  asm("v_cvt_pk_bf16_f32 %0, %1, %2" : "=v"(W) : "v"(p[J + 6]), "v"(p[J + 7]));
  asm("v_permlane32_swap_b32 %0, %1" : "+v"(X), "+v"(Z));
  asm("v_permlane32_swap_b32 %0, %1" : "+v"(Y), "+v"(W));
  union { int w[4]; bf16x8 v; } u;
  u.w[0] = X; u.w[1] = Y; u.w[2] = Z; u.w[3] = W;
  return u.v;
}

// ---------------- prep: f32 -> bf16 elementwise
__global__ __launch_bounds__(256) void cvt_bf16(const float* __restrict__ X,
                                                unsigned short* __restrict__ Y, int n4) {
  int i = blockIdx.x * blockDim.x + threadIdx.x;
  int stride = gridDim.x * blockDim.x;
  for (; i < n4; i += stride) {
    float4 v = reinterpret_cast<const float4*>(X)[i];
    ushort4 o;
    o.x = f2bf(v.x); o.y = f2bf(v.y); o.z = f2bf(v.z); o.w = f2bf(v.w);
    reinterpret_cast<ushort4*>(Y)[i] = o;
  }
}

// ---------------- prep: W[K][N] f32 -> WT[N][K] bf16 (64x64 tiles via LDS)
__global__ __launch_bounds__(256) void transpose_cvt(const float* __restrict__ W,
                                                     unsigned short* __restrict__ WT,
                                                     int K, int N) {
  __shared__ unsigned short Tl[64][72];
  const int t = threadIdx.x;
  const int n0 = blockIdx.x * 64, k0 = blockIdx.y * 64;
#pragma unroll
  for (int i = 0; i < 4; ++i) {
    int idx = t + i * 256;
    int r = idx >> 4, c4 = (idx & 15) << 2;
    float4 v = *reinterpret_cast<const float4*>(&W[(size_t)(k0 + r) * N + n0 + c4]);
    Tl[c4 + 0][r] = f2bf(v.x);
    Tl[c4 + 1][r] = f2bf(v.y);
    Tl[c4 + 2][r] = f2bf(v.z);
    Tl[c4 + 3][r] = f2bf(v.w);
  }
  __syncthreads();
#pragma unroll
  for (int i = 0; i < 2; ++i) {
    int idx = t + i * 256;
    int rr = idx >> 3, cc = (idx & 7) << 3;
    *reinterpret_cast<int4*>(&WT[(size_t)(n0 + rr) * K + k0 + cc]) =
        *reinterpret_cast<const int4*>(&Tl[rr][cc]);
  }
}

// ---------------- GEMM1: BK=64, XOR-swizzled LDS, qkv -> q/k [bh][s][dh], v transposed blocks
__global__ __launch_bounds__(256) void gemm_qkv_b(
    const unsigned short* __restrict__ A, const unsigned short* __restrict__ Bt,
    const float* __restrict__ bias,
    unsigned short* __restrict__ qw, unsigned short* __restrict__ kw,
    unsigned short* __restrict__ vtg) {
  const int K = 1024;
  __shared__ unsigned short Al[8192];
  __shared__ unsigned short Bl[8192];
  const int t = threadIdx.x, lane = t & 63, wid = t >> 6;
  const int wr = (wid >> 1) * 64, wc = (wid & 1) * 64;
  const int row0 = blockIdx.y * 128, col0 = blockIdx.x * 128;
  const int lr = lane & 15, lk = (lane >> 4) * 8, hi4 = lane >> 4;
  // staging: LDS linear, source col pre-swizzled (both-sides rule)
  const int srow = lane >> 3;                       // row offset within 32-row chunk
  const int scol = ((lane & 7) ^ srow) * 8;         // swizzled source col
  const unsigned short* Ab = A + (size_t)row0 * K;
  const unsigned short* Bb = Bt + (size_t)col0 * K;
  f32x4 acc[4][4] = {};
  for (int k0 = 0; k0 < K; k0 += 64) {
#pragma unroll
    for (int i = 0; i < 4; ++i) {
      int r = i * 32 + wid * 8 + srow;
      gload16(&Ab[(size_t)r * K + k0 + scol], &Al[i * 2048 + wid * 512]);
      gload16(&Bb[(size_t)r * K + k0 + scol], &Bl[i * 2048 + wid * 512]);
    }
    asm volatile("s_waitcnt vmcnt(0)" ::: "memory");
    __syncthreads();
#pragma unroll
    for (int ks = 0; ks < 2; ++ks) {
      bf16x8 af[4], bfv[4];
#pragma unroll
      for (int mm = 0; mm < 4; ++mm) {
        int row = wr + mm * 16 + lr;
        af[mm] = *reinterpret_cast<const bf16x8*>(
            &Al[row * 64 + (((ks * 4 + hi4) ^ (row & 7)) << 3)]);
      }
#pragma unroll
      for (int nn = 0; nn < 4; ++nn) {
        int row = wc + nn * 16 + lr;
        bfv[nn] = *reinterpret_cast<const bf16x8*>(
            &Bl[row * 64 + (((ks * 4 + hi4) ^ (row & 7)) << 3)]);
      }
#pragma unroll
      for (int mm = 0; mm < 4; ++mm)
#pragma unroll
        for (int nn = 0; nn < 4; ++nn)
          acc[mm][nn] =
              __builtin_amdgcn_mfma_f32_16x16x32_bf16(af[mm], bfv[nn], acc[mm][nn], 0, 0, 0);
    }
    __syncthreads();
  }
  const int rbase = (lane >> 4) * 4;
#pragma unroll
  for (int mm = 0; mm < 4; ++mm) {
#pragma unroll
    for (int nn = 0; nn < 4; ++nn) {
      int c = col0 + wc + nn * 16 + lr;
      int which = c >> 10;
      int d = c & 1023;
      int h = d >> 6, dh = d & 63;
      float bv = bias[c];
      int m0 = row0 + wr + mm * 16 + rbase;
      int b = m0 >> 11, s0 = m0 & 2047;
      if (which == 2) {
        int kt = s0 >> 6, key0 = s0 & 63;
        ushort4 pv;
        pv.x = f2bf(acc[mm][nn][0] + bv);
        pv.y = f2bf(acc[mm][nn][1] + bv);
        pv.z = f2bf(acc[mm][nn][2] + bv);
        pv.w = f2bf(acc[mm][nn][3] + bv);
        *reinterpret_cast<ushort4*>(
            &vtg[(((size_t)(b * 16 + h) * 32 + kt) * 64 + dh) * 64 + key0]) = pv;
      } else {
        unsigned short* dst = (which == 0) ? qw : kw;
#pragma unroll
        for (int r = 0; r < 4; ++r)
          dst[(((size_t)b * 16 + h) * 2048 + (s0 + r)) * 64 + dh] = f2bf(acc[mm][nn][r] + bv);
      }
    }
  }
}

// ---------------- Flash attention: 8 waves = 4 q-subtiles x 2 key-halves
__global__ __launch_bounds__(512, 4) void attn_kernel(
    const unsigned short* __restrict__ qw, const unsigned short* __restrict__ kw,
    const unsigned short* __restrict__ vtg, unsigned short* __restrict__ ow) {
  // loop phase: KV [half][buf][K 64x64 | V 64x64] bf16 XOR-swizzled = 64 KB
  // epilogue:   Ol [128][72] bf16 (18.4 KB) + EX [4][64][34] f32 (34.8 KB)
  __shared__ char smem[65536];
  unsigned short* KV = (unsigned short*)smem;
  unsigned short* Ol = (unsigned short*)smem;
  float* EX = (float*)(smem + 18432);
  const int t = threadIdx.x, lane = t & 63, wid = t >> 6;
  const int half = wid >> 2, wq = wid & 3;
  const int l31 = lane & 31, hi = lane >> 5;
  const int qt = blockIdx.x, bh = blockIdx.y;
  const int b = bh >> 4, h = bh & 15;
  const unsigned short* Qg = qw + (size_t)bh * 2048 * 64;
  const unsigned short* Kg = kw + (size_t)bh * 2048 * 64;
  const unsigned short* Vg = vtg + (size_t)bh * 32 * 4096;
  const int q0 = qt * 128 + wq * 32;
  const float F = 0.125f * LOG2E;

  union { short s[8]; bf16x8 v; } one_u;
#pragma unroll
  for (int i = 0; i < 8; ++i) one_u.s[i] = (short)0x3F80;
  const bf16x8 ones = one_u.v;

  bf16x8 qf[4];
#pragma unroll
  for (int kc = 0; kc < 4; ++kc)
    qf[kc] = *reinterpret_cast<const bf16x8*>(&Qg[(q0 + l31) * 64 + kc * 16 + hi * 8]);

  f32x16 oA = {0,0,0,0,0,0,0,0,0,0,0,0,0,0,0,0};
  f32x16 oB = {0,0,0,0,0,0,0,0,0,0,0,0,0,0,0,0};
  f32x16 lC = {0,0,0,0,0,0,0,0,0,0,0,0,0,0,0,0};  // l accumulates via ones-MFMA in [0]
  float mrun = -INFINITY;

  const int srow_lo = lane >> 3;
  const int scg = (lane & 7) ^ srow_lo;

#define STAGE(buf, kt)                                                              \
  {                                                                                 \
    const unsigned short* Kt = Kg + (size_t)(kt) * 4096;                            \
    const unsigned short* Vs = Vg + (size_t)(kt) * 4096;                            \
    unsigned short* Kl = KV + half * 16384 + (buf) * 8192;                          \
    unsigned short* Vl = Kl + 4096;                                                 \
    _Pragma("unroll") for (int i = 0; i < 2; ++i) {                                 \
      int chunk = wq * 2 + i;                                                       \
      int row = chunk * 8 + srow_lo;                                                \
      gload16(&Kt[row * 64 + scg * 8], &Kl[chunk * 512]);                           \
      gload16(&Vs[row * 64 + scg * 8], &Vl[chunk * 512]);                           \
    }                                                                               \
  }

  const int kt0 = half * 16;
  STAGE(0, kt0)

  for (int it = 0; it < 16; ++it) {
    const int cur = it & 1;
    if (it + 1 < 16) {
      STAGE(cur ^ 1, kt0 + it + 1)
      asm volatile("s_waitcnt vmcnt(4)" ::: "memory");
    } else {
      asm volatile("s_waitcnt vmcnt(0)" ::: "memory");
    }
    __builtin_amdgcn_s_barrier();
    const unsigned short* Kl = KV + half * 16384 + cur * 8192;
    const unsigned short* Vl = Kl + 4096;

    // S^T = K @ Q^T
    f32x16 sA = {0,0,0,0,0,0,0,0,0,0,0,0,0,0,0,0};
    f32x16 sB = {0,0,0,0,0,0,0,0,0,0,0,0,0,0,0,0};
    __builtin_amdgcn_s_setprio(1);
#pragma unroll
    for (int kc = 0; kc < 4; ++kc) {
      bf16x8 k0f = *reinterpret_cast<const bf16x8*>(
          &Kl[l31 * 64 + (((kc * 2 + hi) ^ (l31 & 7)) << 3)]);
      bf16x8 k1f = *reinterpret_cast<const bf16x8*>(
          &Kl[(32 + l31) * 64 + (((kc * 2 + hi) ^ (l31 & 7)) << 3)]);
      sA = __builtin_amdgcn_mfma_f32_32x32x16_bf16(k0f, qf[kc], sA, 0, 0, 0);
      sB = __builtin_amdgcn_mfma_f32_32x32x16_bf16(k1f, qf[kc], sB, 0, 0, 0);
    }
    __builtin_amdgcn_s_setprio(0);

    // tile max: 3-ary tree with v_max3
    float m0_ = max3f(sA[0], sA[1], sA[2]);
    float m1_ = max3f(sA[3], sA[4], sA[5]);
    float m2_ = max3f(sA[6], sA[7], sA[8]);
    float m3_ = max3f(sA[9], sA[10], sA[11]);
    float m4_ = max3f(sA[12], sA[13], sA[14]);
    float m5_ = max3f(sA[15], sB[0], sB[1]);
    float m6_ = max3f(sB[2], sB[3], sB[4]);
    float m7_ = max3f(sB[5], sB[6], sB[7]);
    float m8_ = max3f(sB[8], sB[9], sB[10]);
    float m9_ = max3f(sB[11], sB[12], sB[13]);
    float ma_ = fmaxf(sB[14], sB[15]);
    float u0 = max3f(m0_, m1_, m2_);
    float u1 = max3f(m3_, m4_, m5_);
    float u2 = max3f(m6_, m7_, m8_);
    float u3 = fmaxf(m9_, ma_);
    float pm = fmaxf(max3f(u0, u1, u2), u3);
    float pmax = fmaxf(pm, __shfl_xor(pm, 32));

    // defer-max (T13)
    if (!__all(pmax - mrun <= 44.0f)) {
      float mnew = fmaxf(mrun, pmax);
      float alpha = exp2f((mrun - mnew) * F);
      mrun = mnew;
      lC[0] *= alpha;
      oA *= alpha;
      oB *= alpha;
    }
    float mF = mrun * F;

#pragma unroll
    for (int j = 0; j < 16; ++j) {
      sA[j] = exp2f(sA[j] * F - mF);
      sB[j] = exp2f(sB[j] * F - mF);
    }

    bf16x8 pf0 = pack_pfrag<0>(sA);
    bf16x8 pf1 = pack_pfrag<8>(sA);
    bf16x8 pf2 = pack_pfrag<0>(sB);
    bf16x8 pf3 = pack_pfrag<8>(sB);

    __builtin_amdgcn_s_setprio(1);
#pragma unroll
    for (int c = 0; c < 4; ++c) {
      bf16x8 pf = (c == 0) ? pf0 : (c == 1) ? pf1 : (c == 2) ? pf2 : pf3;
      int g = c * 2 + hi;
      bf16x8 v0f = *reinterpret_cast<const bf16x8*>(
          &Vl[l31 * 64 + ((g ^ (l31 & 7)) << 3)]);
      bf16x8 v1f = *reinterpret_cast<const bf16x8*>(
          &Vl[(32 + l31) * 64 + ((g ^ (l31 & 7)) << 3)]);
      oA = __builtin_amdgcn_mfma_f32_32x32x16_bf16(v0f, pf, oA, 0, 0, 0);
      oB = __builtin_amdgcn_mfma_f32_32x32x16_bf16(v1f, pf, oB, 0, 0, 0);
      lC = __builtin_amdgcn_mfma_f32_32x32x16_bf16(ones, pf, lC, 0, 0, 0);
    }
    __builtin_amdgcn_s_setprio(0);
    __builtin_amdgcn_s_barrier();
  }
#undef STAGE

  // ---- merge halves + coalesced store via LDS transpose
  __syncthreads();
  if (half == 1) {
    float* e = EX + ((size_t)(wq * 64 + lane)) * 34;
#pragma unroll
    for (int j = 0; j < 16; ++j) { e[j] = oA[j]; e[16 + j] = oB[j]; }
    e[32] = mrun; e[33] = lC[0];
  }
  __syncthreads();
  if (half == 0) {
    const float* e = EX + ((size_t)(wq * 64 + lane)) * 34;
    float m2 = e[32], l2 = e[33];
    float mstar = fmaxf(mrun, m2);
    float a1 = exp2f((mrun - mstar) * F);
    float a2 = exp2f((m2 - mstar) * F);
    float linv = 1.0f / (lC[0] * a1 + l2 * a2);
    float c1 = a1 * linv, c2 = a2 * linv;
    unsigned short* orow_l = Ol + (wq * 32 + l31) * 72;
#pragma unroll
    for (int g = 0; g < 4; ++g) {
      float a0 = oA[4 * g + 0] * c1 + e[4 * g + 0] * c2;
      float a1v = oA[4 * g + 1] * c1 + e[4 * g + 1] * c2;
      float a2v = oA[4 * g + 2] * c1 + e[4 * g + 2] * c2;
      float a3v = oA[4 * g + 3] * c1 + e[4 * g + 3] * c2;
      uint2 w0; w0.x = cvtpk(a0, a1v); w0.y = cvtpk(a2v, a3v);
      *reinterpret_cast<uint2*>(&orow_l[8 * g + 4 * hi]) = w0;
      float b0 = oB[4 * g + 0] * c1 + e[16 + 4 * g + 0] * c2;
      float b1v = oB[4 * g + 1] * c1 + e[16 + 4 * g + 1] * c2;
      float b2v = oB[4 * g + 2] * c1 + e[16 + 4 * g + 2] * c2;
      float b3v = oB[4 * g + 3] * c1 + e[16 + 4 * g + 3] * c2;
      uint2 w1; w1.x = cvtpk(b0, b1v); w1.y = cvtpk(b2v, b3v);
      *reinterpret_cast<uint2*>(&orow_l[32 + 8 * g + 4 * hi]) = w1;
    }
  }
  __syncthreads();
#pragma unroll
  for (int i = 0; i < 2; ++i) {
    int idx = t + i * 512;
    int q = idx >> 3, ch = idx & 7;
    int4 v = *reinterpret_cast<const int4*>(&Ol[q * 72 + ch * 8]);
    *reinterpret_cast<int4*>(
        &ow[(((size_t)b * 2048 + qt * 128 + q) * 16 + h) * 64 + ch * 8]) = v;
  }
}

// ---------------- GEMM2: BK=64, XOR-swizzled LDS, f32 out
__global__ __launch_bounds__(256) void gemm_proj_b(
    const unsigned short* __restrict__ A, const unsigned short* __restrict__ Bt,
    const float* __restrict__ bias, float* __restrict__ out) {
  const int K = 1024, N = 1024;
  __shared__ unsigned short Al[8192];
  __shared__ unsigned short Bl[8192];
  const int t = threadIdx.x, lane = t & 63, wid = t >> 6;
  const int wr = (wid >> 1) * 64, wc = (wid & 1) * 64;
  const int row0 = blockIdx.y * 128, col0 = blockIdx.x * 128;
  const int lr = lane & 15, hi4 = lane >> 4;
  const int srow = lane >> 3;
  const int scol = ((lane & 7) ^ srow) * 8;
  const unsigned short* Ab = A + (size_t)row0 * K;
  const unsigned short* Bb = Bt + (size_t)col0 * K;
  f32x4 acc[4][4] = {};
  for (int k0 = 0; k0 < K; k0 += 64) {
#pragma unroll
    for (int i = 0; i < 4; ++i) {
      int r = i * 32 + wid * 8 + srow;
      gload16(&Ab[(size_t)r * K + k0 + scol], &Al[i * 2048 + wid * 512]);
      gload16(&Bb[(size_t)r * K + k0 + scol], &Bl[i * 2048 + wid * 512]);
    }
    asm volatile("s_waitcnt vmcnt(0)" ::: "memory");
    __syncthreads();
#pragma unroll
    for (int ks = 0; ks < 2; ++ks) {
      bf16x8 af[4], bfv[4];
#pragma unroll
      for (int mm = 0; mm < 4; ++mm) {
        int row = wr + mm * 16 + lr;
        af[mm] = *reinterpret_cast<const bf16x8*>(
            &Al[row * 64 + (((ks * 4 + hi4) ^ (row & 7)) << 3)]);
      }
#pragma unroll
      for (int nn = 0; nn < 4; ++nn) {
        int row = wc + nn * 16 + lr;
        bfv[nn] = *reinterpret_cast<const bf16x8*>(
            &Bl[row * 64 + (((ks * 4 + hi4) ^ (row & 7)) << 3)]);
      }
#pragma unroll
      for (int mm = 0; mm < 4; ++mm)
#pragma unroll
        for (int nn = 0; nn < 4; ++nn)
          acc[mm][nn] =
              __builtin_amdgcn_mfma_f32_16x16x32_bf16(af[mm], bfv[nn], acc[mm][nn], 0, 0, 0);
    }
    __syncthreads();
  }
  const int rbase = (lane >> 4) * 4;
#pragma unroll
  for (int mm = 0; mm < 4; ++mm) {
#pragma unroll
    for (int nn = 0; nn < 4; ++nn) {
      int c = col0 + wc + nn * 16 + lr;
      float bv = bias[c];
#pragma unroll
      for (int r = 0; r < 4; ++r) {
        int m = row0 + wr + mm * 16 + rbase + r;
        out[(size_t)m * N + c] = acc[mm][nn][r] + bv;
      }
    }
  }
}

extern "C" void kernel_launch(void* const* d_in, const int* in_sizes, int n_in,
                              void* d_out, int out_size, void* d_ws, size_t ws_size,
                              hipStream_t stream) {
  const float* hs = (const float*)d_in[0];
  const float* w_attn = (const float*)d_in[1];
  const float* b_attn = (const float*)d_in[2];
  const float* w_proj = (const float*)d_in[3];
  const float* b_proj = (const float*)d_in[4];
  float* out = (float*)d_out;

  const size_t HEAD = (size_t)2 * 16 * 2048 * 64;
  unsigned short* qw = (unsigned short*)d_ws;
  unsigned short* kw = qw + HEAD;
  unsigned short* vtg = kw + HEAD;
  unsigned short* hs_b = vtg + HEAD;
  unsigned short* ow = hs_b;
  unsigned short* wT = hs_b + HEAD;
  unsigned short* pT = wT + (size_t)3072 * 1024;

  cvt_bf16<<<2048, 256, 0, stream>>>(hs, hs_b, 1048576);
  transpose_cvt<<<dim3(48, 16), 256, 0, stream>>>(w_attn, wT, 1024, 3072);
  transpose_cvt<<<dim3(16, 16), 256, 0, stream>>>(w_proj, pT, 1024, 1024);

  gemm_qkv_b<<<dim3(24, 32), 256, 0, stream>>>(hs_b, wT, b_attn, qw, kw, vtg);
  attn_kernel<<<dim3(16, 32), 512, 0, stream>>>(qw, kw, vtg, ow);
  gemm_proj_b<<<dim3(8, 32), 256, 0, stream>>>(ow, pT, b_proj, out);
}